// Round 5
// baseline (3747.327 us; speedup 1.0000x reference)
//
#include <hip/hip_runtime.h>
#include <hip/hip_bf16.h>

// SimpleBiGRU on MI355X — R4b: tagged-data poll (flag fused into data words).
// Both "directions" are forward-in-time GRU scans (batch-flip is identity).
// 8 units = (dir) x (batch-group of 16 rows); 32 WGs (1 wave each) per unit,
// each owning 16 hidden columns x 3 gates.
//
// h broadcast format: u32 = (bf16 value << 16) | tag, tag = step+1 at publish.
// Consumer at step t polls its own 32 MFMA-fragment chunks (16B each) until
// ALL tags == t, then uses the values already sitting in registers. No flags,
// no producer-side drain, no separate data-load RTT. Publish = two 8B
// agent-scope atomic stores per lane (asm dwordx4 input constraint is
// unsupported); tag words 0 and 3 of each 16B chunk cover both 8B granules.
// Double buffer + "every WG is both producer and consumer" => nobody runs
// >1 step ahead => no overwrite hazard.
//
// MFMA convention (swapped, layout-safe k-slot mapping k = ks*32 + lg*8 + j):
//   acc = MFMA(W_frag, act_frag, acc); D: row = 4*lg+reg = out-col offset,
//   col = l15 = batch row. Lane owns 4 adjacent h-cols of one batch row.

#define TT 512
#define FF 256
#define HH 512
#define G3 1536
#define NWG 256
#define NTHR 64

typedef __attribute__((ext_vector_type(8))) short short8;   // 8 x bf16
typedef __attribute__((ext_vector_type(4))) float f32x4;
typedef unsigned int u32;
typedef unsigned long long u64;

union U4 { uint4 v; u32 u[4]; u64 q[2]; };

__device__ __forceinline__ unsigned short f2bf(float f) {
  union { float f; unsigned u; } x; x.f = f;
  return (unsigned short)((x.u + 0x7fffu + ((x.u >> 16) & 1u)) >> 16);  // RNE
}

__device__ __forceinline__ unsigned pk2(float a, float b) {
  union { __hip_bfloat162 h; unsigned u; } x;
  x.h = __float22bfloat162_rn(make_float2(a, b));
  return x.u;  // low 16 = a, high 16 = b
}

__device__ __forceinline__ float sigm(float x) {
  return __builtin_amdgcn_rcpf(1.f + __expf(-x));
}

#define MFMA(a, b, c) __builtin_amdgcn_mfma_f32_16x16x32_bf16((a), (b), (c), 0, 0, 0)

__global__ __launch_bounds__(NTHR, 1) void gru_fused(
    const float* __restrict__ data,
    const float* __restrict__ Wi_f, const float* __restrict__ bi_f,
    const float* __restrict__ Wh_f, const float* __restrict__ bhn_f,
    const float* __restrict__ Wi_b, const float* __restrict__ bi_b,
    const float* __restrict__ Wh_b, const float* __restrict__ bhn_b,
    float* __restrict__ out,
    u32* __restrict__ hbuf)   // [unit][buf][row16][col512] tagged u32
{
  const int wg   = blockIdx.x;
  const int unit = wg & 7;      // same-XCD heuristic for a unit's 32 WGs
  const int s    = wg >> 3;     // column slice 0..31
  const int dir  = unit >> 2;
  const int bg   = unit & 3;
  const int lane = threadIdx.x; // 0..63
  const int l15  = lane & 15;
  const int lg   = lane >> 4;

  const float* Wi  = dir ? Wi_b  : Wi_f;
  const float* Wh  = dir ? Wh_b  : Wh_f;
  const float* bi  = dir ? bi_b  : bi_f;
  const float* bhn = dir ? bhn_b : bhn_f;

  const int colT = s * 16 + l15;        // weight-fragment column (A m-index)
  const int colBase = s * 16 + lg * 4;  // this lane's 4 output columns

  // ---- one-time: weight A-fragments into registers (k = ks*32+lg*8+j) ----
  short8 whf[3][16];
#pragma unroll
  for (int g = 0; g < 3; ++g)
#pragma unroll
    for (int ks = 0; ks < 16; ++ks) {
      short8 v;
#pragma unroll
      for (int j = 0; j < 8; ++j)
        v[j] = (short)f2bf(Wh[(size_t)(ks * 32 + lg * 8 + j) * G3 + g * HH + colT]);
      whf[g][ks] = v;
    }
  short8 wif[3][8];
#pragma unroll
  for (int g = 0; g < 3; ++g)
#pragma unroll
    for (int ks = 0; ks < 8; ++ks) {
      short8 v;
#pragma unroll
      for (int j = 0; j < 8; ++j)
        v[j] = (short)f2bf(Wi[(size_t)(ks * 32 + lg * 8 + j) * G3 + g * HH + colT]);
      wif[g][ks] = v;
    }
  float biR[4], biZ[4], biN[4], bhc[4];
#pragma unroll
  for (int j = 0; j < 4; ++j) {
    biR[j] = bi[colBase + j];
    biZ[j] = bi[HH + colBase + j];
    biN[j] = bi[2 * HH + colBase + j];
    bhc[j] = bhn[colBase + j];
  }

  const float* xbase = data + (size_t)(bg * 16 + l15) * TT * FF;
  float hp[4] = {0.f, 0.f, 0.f, 0.f};  // fp32 carry: batch l15, cols colBase+j

  for (int t = 0; t < TT; ++t) {
    // ---- xg phase (h-independent; issues before the poll, hides under it) --
    f32x4 accR = {0.f, 0.f, 0.f, 0.f};
    f32x4 accZ = {0.f, 0.f, 0.f, 0.f};
    f32x4 xN   = {0.f, 0.f, 0.f, 0.f};
    {
      const float* xr = xbase + (size_t)t * FF;
#pragma unroll
      for (int ks = 0; ks < 8; ++ks) {
        float4 x0 = *(const float4*)(xr + ks * 32 + lg * 8);
        float4 x1 = *(const float4*)(xr + ks * 32 + lg * 8 + 4);
        union { short8 s; unsigned u[4]; } a;
        a.u[0] = pk2(x0.x, x0.y); a.u[1] = pk2(x0.z, x0.w);
        a.u[2] = pk2(x1.x, x1.y); a.u[3] = pk2(x1.z, x1.w);
        accR = MFMA(wif[0][ks], a.s, accR);
        accZ = MFMA(wif[1][ks], a.s, accZ);
        xN   = MFMA(wif[2][ks], a.s, xN);
      }
    }

    // ---- tagged poll: reload own fragments until all 32 chunk-tags == t ----
    const u32 tag = (u32)t;
    const u32* hb = hbuf + ((size_t)(unit * 2 + (t & 1)) << 13);  // 16*512 u32
    U4 q[32];
    while (true) {
#pragma unroll
      for (int ks = 0; ks < 16; ++ks) {
        const u32* p = hb + l15 * 512 + ks * 32 + lg * 8;
        asm volatile("global_load_dwordx4 %0, %1, off sc0 sc1"
                     : "=v"(q[2 * ks].v) : "v"(p));
        asm volatile("global_load_dwordx4 %0, %1, off sc0 sc1"
                     : "=v"(q[2 * ks + 1].v) : "v"(p + 4));
      }
      asm volatile("s_waitcnt vmcnt(0)" ::: "memory");
      u32 bad = 0;
#pragma unroll
      for (int c = 0; c < 32; ++c) {
        bad |= (q[c].u[0] ^ tag) & 0xffffu;   // tag of 8B granule {w0,w1}
        bad |= (q[c].u[3] ^ tag) & 0xffffu;   // tag of 8B granule {w2,w3}
      }
      if (__all(bad == 0)) break;
    }

    // ---- pack B-fragments (strip tags; high16 of pair -> bf16x2) ----
    // and hg MFMAs
    f32x4 hN = {0.f, 0.f, 0.f, 0.f};
#pragma unroll
    for (int ks = 0; ks < 16; ++ks) {
      union { short8 s; unsigned u[4]; } a;
#pragma unroll
      for (int i = 0; i < 2; ++i) {
        const U4& c = q[2 * ks + i];
        a.u[2 * i]     = __builtin_amdgcn_perm(c.u[1], c.u[0], 0x07060302u);
        a.u[2 * i + 1] = __builtin_amdgcn_perm(c.u[3], c.u[2], 0x07060302u);
      }
      accR = MFMA(whf[0][ks], a.s, accR);
      accZ = MFMA(whf[1][ks], a.s, accZ);
      hN   = MFMA(whf[2][ks], a.s, hN);
    }

    // ---- gates: lane holds (batch=l15, cols=colBase..+3) ----
    float hv[4];
#pragma unroll
    for (int j = 0; j < 4; ++j) {
      float r = sigm(accR[j] + biR[j]);
      float z = sigm(accZ[j] + biZ[j]);
      float e = __expf(2.f * (xN[j] + biN[j] + r * (hN[j] + bhc[j])));
      float n = 1.f - 2.f * __builtin_amdgcn_rcpf(e + 1.f);  // tanh
      hv[j] = (1.f - z) * n + z * hp[j];
      hp[j] = hv[j];
    }

    // ---- publish: two tagged 8B atomic stores, no drain, no flag ----
    {
      U4 w;
      const u32 wtag = (u32)(t + 1);
#pragma unroll
      for (int j = 0; j < 4; ++j)
        w.u[j] = ((u32)f2bf(hv[j]) << 16) | wtag;
      u32* ho = hbuf + ((size_t)(unit * 2 + ((t + 1) & 1)) << 13);
      u64* pdst = (u64*)(ho + l15 * 512 + s * 16 + lg * 4);
      __hip_atomic_store(&pdst[0], w.q[0], __ATOMIC_RELAXED, __HIP_MEMORY_SCOPE_AGENT);
      __hip_atomic_store(&pdst[1], w.q[1], __ATOMIC_RELAXED, __HIP_MEMORY_SCOPE_AGENT);
    }

    // ---- out store (off critical path): one float4 per lane ----
    *(float4*)(out + ((size_t)(bg * 16 + l15) * TT + t) * 1024 + (size_t)dir * HH + colBase)
        = make_float4(hv[0], hv[1], hv[2], hv[3]);
  }
}

extern "C" void kernel_launch(void* const* d_in, const int* in_sizes, int n_in,
                              void* d_out, int out_size, void* d_ws, size_t ws_size,
                              hipStream_t stream) {
  const float* data  = (const float*)d_in[0];
  const float* Wi_f  = (const float*)d_in[1];
  const float* bi_f  = (const float*)d_in[2];
  const float* Wh_f  = (const float*)d_in[3];
  const float* bhn_f = (const float*)d_in[4];
  const float* Wi_b  = (const float*)d_in[5];
  const float* bi_b  = (const float*)d_in[6];
  const float* Wh_b  = (const float*)d_in[7];
  const float* bhn_b = (const float*)d_in[8];
  float* out = (float*)d_out;

  // ws: [0, 512KB) tagged h double buffers (8 units x 2 x 16 x 512 u32).
  // memset(0) == valid tag-0 zero state => uniform t=0 path.
  u32* hbuf = (u32*)d_ws;
  (void)hipMemsetAsync(d_ws, 0, 524288, stream);

  gru_fused<<<NWG, NTHR, 0, stream>>>(data, Wi_f, bi_f, Wh_f, bhn_f,
                                      Wi_b, bi_b, Wh_b, bhn_b, out, hbuf);
}